// Round 8
// baseline (276.827 us; speedup 1.0000x reference)
//
#include <hip/hip_runtime.h>
#include <hip/hip_bf16.h>

// MultiHeadSelfAttention: B=4, T=2048, D=1024, H=16, dk=64
// Pipeline: fused prepass -> QKV GEMM (256^2 8-phase, m201-style) ->
//           flash attention (R1 structure) -> out GEMM (m97-style)
//
// R8 = R7 (262.4 us, best) + faithful m201 8-phase port for qkv_gemm ONLY.
// R5/R6 failed because they were a COARSE 2-phase + vmcnt (m196's -7..-27%
// case). This is the fine interleave: phase = C-quadrant, 16 MFMA/phase,
// 2 raw s_barrier/phase, 1 half-tile staged/phase into a region proven
// free by the release schedule (B free after q0, A after q3), counted
// vmcnt(4) at q0 only (2 half-tiles x 2 loads legitimately in flight),
// vmcnt(0) only at the last K-tile. T5 setprio inside phases (m218b:
// +21-25% WITH phase role-split). out_gemm stays gemm128 as control.
//
// Workspace layout (bytes), total 92,274,688 (88 MiB):
//   XB   @ 0         : x as bf16              [8192][1024]        16 MiB
//   WQT  @ 16777216  : w_qkv^T as bf16        [3072][1024]         6 MiB
//   WOT  @ 23068672  : w_out^T as bf16        [1024][1024]         2 MiB
//   Q    @ 25165824  : bf16 [4][16][2048][64] (pre-scaled)        16 MiB
//   K    @ 41943040  : bf16 [4][16][2048][64]                     16 MiB
//   VT   @ 58720256  : bf16 [4][16][64][2048]  (V transposed)     16 MiB
//   CTX  @ 75497472  : bf16 [8192][1024]                          16 MiB

using v8bf  = __attribute__((ext_vector_type(8))) __bf16;
using f32x4 = __attribute__((ext_vector_type(4))) float;
using f32x16 = __attribute__((ext_vector_type(16))) float;
typedef unsigned int uv2 __attribute__((ext_vector_type(2)));

__device__ __forceinline__ unsigned short f2bf(float f) {
  union { float f; unsigned int u; } v; v.f = f;
  unsigned int u = v.u;
  u += 0x7FFFu + ((u >> 16) & 1u);   // round-to-nearest-even
  return (unsigned short)(u >> 16);
}

#if __has_builtin(__builtin_amdgcn_cvt_pk_bf16_f32)
__device__ __forceinline__ unsigned int pack2bf(float a, float b) {
  typedef __bf16 bf16x2 __attribute__((ext_vector_type(2)));
  bf16x2 r = __builtin_amdgcn_cvt_pk_bf16_f32(a, b);   // dst.lo=a, dst.hi=b
  return __builtin_bit_cast(unsigned int, r);
}
#else
__device__ __forceinline__ unsigned int pack2bf(float a, float b) {
  return (unsigned int)f2bf(a) | ((unsigned int)f2bf(b) << 16);
}
#endif

// async global->LDS, 16B per lane. LDS dest = wave-uniform base + lane*16.
__device__ __forceinline__ void async16(const void* g, void* l) {
  __builtin_amdgcn_global_load_lds(
      (__attribute__((address_space(1))) void*)g,
      (__attribute__((address_space(3))) void*)l, 16, 0, 0);
}

// ---------------- Kernel 0: fused prepass ----------------
// blocks [0,8192):    x fp32 -> bf16 contiguous (4 floats/thread)
// blocks [8192,8960): w_qkv [1024][3072] -> WQT [3072][1024] (64x64 tiles)
// blocks [8960,9216): w_out [1024][1024] -> WOT [1024][1024]
__global__ __launch_bounds__(256) void prepass(const float* __restrict__ x,
                                               unsigned short* __restrict__ XB,
                                               const float* __restrict__ wq,
                                               unsigned short* __restrict__ WQT,
                                               const float* __restrict__ wo,
                                               unsigned short* __restrict__ WOT) {
  const int bid = blockIdx.x;
  if (bid < 8192) {
    const int i = (bid * 256 + threadIdx.x) * 4;
    float4 v = *(const float4*)(x + i);
    ushort4 o;
    o.x = f2bf(v.x); o.y = f2bf(v.y); o.z = f2bf(v.z); o.w = f2bf(v.w);
    *(ushort4*)(XB + i) = o;
  } else {
    const float* in; unsigned short* out; int N, tb;
    if (bid < 8960) { in = wq; out = WQT; N = 3072; tb = bid - 8192; }
    else            { in = wo; out = WOT; N = 1024; tb = bid - 8960; }
    __shared__ unsigned short tile[64][65];
    const int k0 = (tb & 15) * 64, n0 = (tb >> 4) * 64;   // K=1024 -> 16 k-tiles
    for (int i = threadIdx.x; i < 4096; i += 256) {
      int r = i >> 6, c = i & 63;
      tile[r][c] = f2bf(in[(size_t)(k0 + r) * N + n0 + c]);
    }
    __syncthreads();
    for (int i = threadIdx.x; i < 4096; i += 256) {
      int r = i >> 6, c = i & 63;
      out[(size_t)(n0 + r) * 1024 + k0 + c] = tile[c][r];
    }
  }
}

// ---------------- m97-style GEMM mainloop (out_gemm only) ----------------
__device__ __forceinline__ void gemm128(const unsigned short* __restrict__ A,
                                        const unsigned short* __restrict__ Bt,
                                        int m0, int n0,
                                        unsigned short* As, unsigned short* Bs,
                                        f32x4 acc[4][4]) {
  const int tid = threadIdx.x;
  const int w = tid >> 6, lane = tid & 63, quad = lane >> 4, l16 = lane & 15;
  const int wm = (w >> 1) * 64, wn = (w & 1) * 64;

  const int srow = w * 32 + (lane >> 3);
  const int cg = (lane & 7) ^ (lane >> 3);
  const size_t a_g = (size_t)(m0 + srow) * 1024 + cg * 8;
  const size_t b_g = (size_t)(n0 + srow) * 1024 + cg * 8;
  const int lds_off = srow * 64 + (lane & 7) * 8;

  const int l7 = l16 & 7;
  const int a_rd0 = (wm + l16) * 128 + ((quad ^ l7) << 4);
  const int a_rd1 = (wm + l16) * 128 + (((4 + quad) ^ l7) << 4);
  const int b_rd0 = (wn + l16) * 128 + ((quad ^ l7) << 4);
  const int b_rd1 = (wn + l16) * 128 + (((4 + quad) ^ l7) << 4);

  for (int k0 = 0; k0 < 1024; k0 += 64) {
#pragma unroll
    for (int j = 0; j < 4; j++) {
      async16(A + a_g + (size_t)j * 8192 + k0, As + lds_off + j * 512);
      async16(Bt + b_g + (size_t)j * 8192 + k0, Bs + lds_off + j * 512);
    }
    __syncthreads();
#pragma unroll
    for (int ks = 0; ks < 2; ks++) {
      v8bf af[4], bfr[4];
#pragma unroll
      for (int i = 0; i < 4; i++) {
        af[i]  = *(const v8bf*)((const char*)As + (ks ? a_rd1 : a_rd0) + i * 2048);
        bfr[i] = *(const v8bf*)((const char*)Bs + (ks ? b_rd1 : b_rd0) + i * 2048);
      }
#pragma unroll
      for (int i = 0; i < 4; i++)
#pragma unroll
        for (int jn = 0; jn < 4; jn++)
          acc[i][jn] = __builtin_amdgcn_mfma_f32_16x16x32_bf16(af[i], bfr[jn], acc[i][jn], 0, 0, 0);
    }
    __syncthreads();
  }
}

// ---------------- Kernel 1: QKV GEMM, 256^2 8-phase ----------------
// 512 threads / 8 waves (2M x 4N), per-wave 128x64 C = acc[8][4].
// LDS: A 2x[256][64] (64KB) + B 2x[256][64] (64KB) = 128 KiB, 1 block/CU.
// Phase = one C-quadrant (32 rows) x K=64 = 16 MFMA. 4 phases/K-tile,
// 16 K-tiles (K=1024). Per phase: ds-reads (q0: B 8 + A 4; else A 4),
// stage ONE half-tile (128 rows x 64 K, 2 gload_lds/thread) into a
// region freed by the release schedule:
//   q0 -> A(kt+1)h0   (A buf kt+1 parity: released after kt-1 q3)
//   q1 -> A(kt+1)h1
//   q2 -> B(kt+2)h0   (B buf kt parity: released after kt q0)
//   q3 -> B(kt+2)h1
// vmcnt(4) at q0 (halves staged after K-tile kt's last: exactly B(kt+1)
// h0/h1 = 4 loads); vmcnt(0) at kt=15 q0. Never drained elsewhere.
__global__ __launch_bounds__(512, 2) void qkv_gemm(const unsigned short* __restrict__ xb,
                                                   const unsigned short* __restrict__ wt,
                                                   const float* __restrict__ bias,
                                                   unsigned short* __restrict__ Q,
                                                   unsigned short* __restrict__ K,
                                                   unsigned short* __restrict__ VT) {
  __shared__ __align__(16) unsigned char pool[131072];        // 128 KiB
  unsigned short* AsL = (unsigned short*)pool;                // 2 x 32 KB
  unsigned short* BsL = (unsigned short*)(pool + 65536);      // 2 x 32 KB
  unsigned short* Tr  = (unsigned short*)pool;                // reused post-GEMM

  const int tid = threadIdx.x;
  const int wid = tid >> 6, lane = tid & 63;
  const int quad = lane >> 4, l16 = lane & 15, l7 = l16 & 7;
  const int wm = (wid >> 2) * 128, wn = (wid & 3) * 64;

  // XCD-bijective swizzle (384 % 8 == 0)
  const int id = blockIdx.x;
  const int swz = (id & 7) * 48 + (id >> 3);
  const int mt = swz & 31, nt = swz >> 5;     // 32 x 12
  const int m0 = mt * 256, n0 = nt * 256;

  const int cg = (lane & 7) ^ (lane >> 3);    // pre-swizzled global chunk

  f32x4 acc[8][4];
#pragma unroll
  for (int i = 0; i < 8; i++)
#pragma unroll
    for (int j = 0; j < 4; j++) acc[i][j] = (f32x4){0.f, 0.f, 0.f, 0.f};

  // stage one 128x64 half-tile (2 x gload_lds / thread, 16B each)
  auto stageHalf = [&](int isB, int h, int kt) {
    const unsigned short* G = isB ? wt : xb;
    const int rbase = (isB ? n0 : m0) + h * 128;
    unsigned short* dst = (isB ? BsL : AsL) + (kt & 1) * 16384 + h * 8192
                          + wid * 512 + lane * 8;   // = uniform + lane*16B
#pragma unroll
    for (int j = 0; j < 2; j++)
      async16(G + (size_t)(rbase + j * 64 + wid * 8 + (lane >> 3)) * 1024
                + kt * 64 + cg * 8,
              dst + j * 4096);
  };

  // prologue: B0h0,B0h1,A0h0,A0h1,B1h0,B1h1 (6 halves, 12 loads/thread)
  stageHalf(1, 0, 0); stageHalf(1, 1, 0);
  stageHalf(0, 0, 0); stageHalf(0, 1, 0);
  stageHalf(1, 0, 1); stageHalf(1, 1, 1);
  asm volatile("s_waitcnt vmcnt(4)" ::: "memory");   // K-tile 0 complete
  __builtin_amdgcn_s_barrier();

  const int rB = wn & 64;                  // row base within B half
  v8bf bfr[4][2];                          // B-frags persist across a K-tile

  for (int kt = 0; kt < 16; ++kt) {
    const unsigned short* Ah = AsL + (kt & 1) * 16384 + (wid >> 2) * 8192;
    const unsigned short* Bh = BsL + (kt & 1) * 16384 + ((wid >> 1) & 1) * 8192;
#pragma unroll
    for (int q = 0; q < 4; ++q) {
      if (q == 0) {
        if (kt == 15)     asm volatile("s_waitcnt vmcnt(0)" ::: "memory");
        else if (kt > 0)  asm volatile("s_waitcnt vmcnt(4)" ::: "memory");
      }
      // ds-reads for this phase
      if (q == 0) {
#pragma unroll
        for (int j = 0; j < 4; j++)
#pragma unroll
          for (int ks = 0; ks < 2; ks++)
            bfr[j][ks] = *(const v8bf*)((const char*)Bh +
                (rB + j * 16 + l16) * 128 + (((ks * 4 + quad) ^ l7) << 4));
      }
      v8bf af[2][2];
#pragma unroll
      for (int i = 0; i < 2; i++)
#pragma unroll
        for (int ks = 0; ks < 2; ks++)
          af[i][ks] = *(const v8bf*)((const char*)Ah +
              (q * 32 + i * 16 + l16) * 128 + (((ks * 4 + quad) ^ l7) << 4));
      // stage one half-tile into a released region
      if (q <= 1) { if (kt < 15) stageHalf(0, q, kt + 1); }
      else        { if (kt < 14) stageHalf(1, q - 2, kt + 2); }
      if (q == 0) asm volatile("s_waitcnt lgkmcnt(8)" ::: "memory");
      __builtin_amdgcn_s_barrier();
      asm volatile("s_waitcnt lgkmcnt(0)" ::: "memory");
      __builtin_amdgcn_s_setprio(1);
#pragma unroll
      for (int i = 0; i < 2; i++)
#pragma unroll
        for (int ks = 0; ks < 2; ks++)
#pragma unroll
          for (int j = 0; j < 4; j++)
            acc[q * 2 + i][j] = __builtin_amdgcn_mfma_f32_16x16x32_bf16(
                af[i][ks], bfr[j][ks], acc[q * 2 + i][j], 0, 0, 0);
      __builtin_amdgcn_s_setprio(0);
      __builtin_amdgcn_s_barrier();
    }
  }

  // ---------------- epilogue ----------------
  const int seg = n0 >> 10;
  if (seg < 2) {
    const float sc = (seg == 0) ? 0.18033688011112042f : 1.0f;  // 0.125*log2(e)
    unsigned short* dst = (seg == 0) ? Q : K;
#pragma unroll
    for (int j = 0; j < 4; j++) {
      const int n = n0 + wn + j * 16 + l16;
      const float bv = bias[n];
      const int nn = n & 1023, h = nn >> 6, d = nn & 63;
#pragma unroll
      for (int i = 0; i < 8; i++) {
#pragma unroll
        for (int r = 0; r < 4; r++) {
          const int m = m0 + wm + i * 16 + quad * 4 + r;
          const int b_ = m >> 11, t = m & 2047;
          dst[(((size_t)(b_ * 16 + h)) * 2048 + t) * 64 + d] =
              f2bf((acc[i][j][r] + bv) * sc);
        }
      }
    }
  } else {
    // V: transpose 256x256 tile via LDS in two 128-col passes
    const int TP = 136;
#pragma unroll
    for (int ph = 0; ph < 2; ph++) {
      if ((wid >> 2) == ph) {
#pragma unroll
        for (int j = 0; j < 4; j++) {
          const int nl = wn + j * 16 + l16;          // 0..255
          const float bv = bias[n0 + nl];
#pragma unroll
          for (int i = 0; i < 8; i++) {
            const int ml = i * 16 + quad * 4;        // local col 0..127
            ushort4 v4;
            v4.x = f2bf(acc[i][j][0] + bv);
            v4.y = f2bf(acc[i][j][1] + bv);
            v4.z = f2bf(acc[i][j][2] + bv);
            v4.w = f2bf(acc[i][j][3] + bv);
            *(ushort4*)&Tr[nl * TP + ml] = v4;
          }
        }
      }
      __syncthreads();
      {
        const int rl = tid >> 1, cb = (tid & 1) * 64;
        const int h0 = (n0 & 1023) >> 6;
        const int h = h0 + (rl >> 6), d = rl & 63;
        const int b_ = m0 >> 11;
        const int t0 = (m0 & 2047) + ph * 128 + cb;
        unsigned short* dstp = VT + (((size_t)(b_ * 16 + h)) * 64 + d) * 2048 + t0;
        const unsigned short* src = &Tr[rl * TP + cb];
#pragma unroll
        for (int c = 0; c < 8; c++)   // 8 x uint4 = 64 shorts
          *(uint4*)(dstp + c * 8) = *(const uint4*)(src + c * 8);
      }
      __syncthreads();
    }
  }
}

// ---------------- Kernel 2: flash attention (S^T, pipelined softmax) ----------------
// EXACT R1 structure (89.6-91 us measured). Grid (x=bh 64, y=qtile 8): XCD = bh%8.
// Step i body: softmax(st of tile i-1) [VALU] + S(tile i) [matrix, K LDS] +
// PV(i-1) [matrix, V LDS]. 64-s K/V tiles, TRIPLE-buffered. One barrier/step.
__global__ __launch_bounds__(256, 2) void flash_attn(const unsigned short* __restrict__ Q,
                                                     const unsigned short* __restrict__ K,
                                                     const unsigned short* __restrict__ VT,
                                                     unsigned short* __restrict__ ctx) {
  const int bh    = blockIdx.x;   // 0..63  (x: keeps same-bh blocks on one XCD)
  const int qtile = blockIdx.y;   // 0..7
  const int tid = threadIdx.x;
  const int w = tid >> 6, lane = tid & 63, hi = lane >> 5, l32 = lane & 31;
  const int q0 = qtile * 256;

  const unsigned short* Qb = Q  + (size_t)bh * 2048 * 64;
  const unsigned short* Kb = K  + (size_t)bh * 2048 * 64;
  const unsigned short* Vb = VT + (size_t)bh * 64 * 2048;

  // triple-buffered K [64 s][64 dk] and V [64 dk][64 s] tiles, XOR-swizzled
  // 16B chunks (slot = chunk ^ (row&7)) for conflict-free b128 reads.
  __shared__ __align__(16) unsigned short Ks[3 * 4096];
  __shared__ __align__(16) unsigned short Vs[3 * 4096];

  const int sr = w * 8 + (lane >> 3);
  const int cg = (lane & 7) ^ ((lane >> 3) & 7);
  const int lds_off = sr * 64 + (lane & 7) * 8;

  // persistent Q B-frags for 2 q-tiles (Q pre-scaled by 0.125*log2e)
  v8bf qf[2][4];
#pragma unroll
  for (int qt = 0; qt < 2; qt++) {
    const int qrow = q0 + w * 64 + qt * 32 + l32;
#pragma unroll
    for (int kc = 0; kc < 4; kc++)
      qf[qt][kc] = *(const v8bf*)(Qb + (size_t)qrow * 64 + kc * 16 + hi * 8);
  }

  f32x16 o[2][2];     // [qt][mt] O^T accumulators
  f32x16 st[2][2];    // [qt][sf] score/prob tile, pipelined across steps
  float l_[2] = {0.f, 0.f};
#pragma unroll
  for (int qt = 0; qt < 2; qt++)
#pragma unroll
    for (int mt = 0; mt < 2; mt++)
#pragma unroll
      for (int r = 0; r < 16; r++) o[qt][mt][r] = 0.f;

  // persistent zero C-operand: computeS seeds its first MFMA from this
  // instead of 64 v_mov zero-fills per step (costs 16 VGPRs, saves ~128cy/step)
  f32x16 fz;
#pragma unroll
  for (int r = 0; r < 16; r++) fz[r] = 0.f;

  auto stage = [&](int buf, int s0) {
    unsigned short* Kd = Ks + buf * 4096;
    unsigned short* Vd = Vs + buf * 4096;
#pragma unroll
    for (int j = 0; j < 2; j++) {
      async16(Kb + (size_t)(s0 + sr + j * 32) * 64 + cg * 8, Kd + lds_off + j * 2048);
      async16(Vb + (size_t)(sr + j * 32) * 2048 + s0 + cg * 8, Vd + lds_off + j * 2048);
    }
  };

  const int l7 = l32 & 7;

  // S^T(tile) = K_tile . Q^T into st (fresh accumulate, C seeded from fz)
  auto computeS = [&](const unsigned short* Kc) {
#pragma unroll
    for (int sf = 0; sf < 2; sf++) {
      v8bf ak[4];
#pragma unroll
      for (int kc = 0; kc < 4; kc++)
        ak[kc] = *(const v8bf*)((const char*)Kc +
                   (sf * 32 + l32) * 128 + (((2 * kc + hi) ^ l7) << 4));
#pragma unroll
      for (int qt = 0; qt < 2; qt++) {
        f32x16 s = __builtin_amdgcn_mfma_f32_32x32x16_bf16(ak[0], qf[qt][0], fz, 0, 0, 0);
#pragma unroll
        for (int kc = 1; kc < 4; kc++)
          s = __builtin_amdgcn_mfma_f32_32x32x16_bf16(ak[kc], qf[qt][kc], s, 0, 0, 0);
        st[qt][sf] = s;
      }
    }
  };

  // exp2(st) in place, accumulate l, pack to bf16 pairs (frees st for next S)
  auto softmax_pack = [&](uint2 pk[2][2][4]) {
#pragma unroll
    for (int qt = 0; qt < 2; qt++) {
      float a = 0.f;
#pragma unroll
      for (int sf = 0; sf < 2; sf++)
#pragma unroll
        for (int r = 0; r < 16; r++) {
          const float pv = __builtin_amdgcn_exp2f(st[qt][sf][r]);
          st[qt][sf][r] = pv;
          a += pv;
        }
      l_[qt] += a;
#pragma unroll
      for (int sf = 0; sf < 2; sf++)
#pragma unroll
        for (int g = 0; g < 4; g++) {
          pk[qt][sf][g].x = pack2bf(st[qt][sf][g * 4 + 0], st[qt][sf][g * 4 + 1]);
          pk[qt][sf][g].y = pack2bf(st[qt][sf][g * 4 + 2], st[qt][sf][g * 4 + 3]);
        }
    }
  };

  // C-layout -> B-frag half-swap transform + PV accumulate.
  // v_permlane32_swap_b32(a,b): a' = {a.lo, b.lo}, b' = {a.hi, b.hi} — one
  // instruction yields BOTH B-frag words; replaces ds_bpermute shfl + selects.
  auto pv = [&](const unsigned short* Vc, uint2 pk[2][2][4]) {
    v8bf vf[2][4];
#pragma unroll
    for (int mt = 0; mt < 2; mt++)
#pragma unroll
      for (int kc = 0; kc < 4; kc++)
        vf[mt][kc] = *(const v8bf*)((const char*)Vc +
                       (mt * 32 + l32) * 128 + (((2 * kc + hi) ^ l7) << 4));
#pragma unroll
    for (int qt = 0; qt < 2; qt++) {
#pragma unroll
      for (int kc = 0; kc < 4; kc++) {
        const int sf = kc >> 1, c2 = (kc & 1) * 2;
        const uint2 olo = pk[qt][sf][c2];
        const uint2 ohi = pk[qt][sf][c2 + 1];
        uint4 u;
#if __has_builtin(__builtin_amdgcn_permlane32_swap)
        uv2 rx = __builtin_amdgcn_permlane32_swap(olo.x, ohi.x, false, false);
        uv2 ry = __builtin_amdgcn_permlane32_swap(olo.y, ohi.y, false, false);
        u.x = rx[0]; u.y = ry[0]; u.z = rx[1]; u.w = ry[1];
#else
        uint2 send, recv;
        send.x = hi ? olo.x : ohi.x;
        send.y = hi ? olo.y : ohi.y;
        recv.x = __shfl_xor(send.x, 32, 64);
        recv.y = __shfl_xor(send.y, 32, 64);
        u.x = hi ? recv.x : olo.x;
        u.y = hi ? recv.y : olo.y;
        u.z = hi ? ohi.x : recv.x;
        u.w = hi ? ohi.y : recv.y;
#endif
        const v8bf pf = __builtin_bit_cast(v8bf, u);
#pragma unroll
        for (int mt = 0; mt < 2; mt++)
          o[qt][mt] = __builtin_amdgcn_mfma_f32_32x32x16_bf16(vf[mt][kc], pf, o[qt][mt], 0, 0, 0);
      }
    }
  };

  // ---- prologue: stage tiles 0,1; S(0) ----
  stage(0, 0);
  __syncthreads();          // tile 0 visible
  stage(1, 64);             // into buf 1; drained by the it=1 barrier
  computeS(Ks);             // st = S(tile 0)

  // ---- pipelined main loop: step it handles softmax+PV of it-1, S of it ----
  // rotating buffer indices (cs = it%3, cp = (it-1)%3, cn = (it+1)%3)
  int cs = 1, cp = 0, cn = 2;
  for (int it = 1; it < 32; ++it) {
    __syncthreads();        // stage(it) done; all waves released buf (it+1)%3
    if (it < 31) stage(cn, (it + 1) * 64);
    uint2 pk[2][2][4];
    softmax_pack(pk);                        // VALU/trans on tile it-1
    computeS(Ks + cs * 4096);                // matrix: S(tile it) -> st
    pv(Vs + cp * 4096, pk);                  // matrix+DS: O += P(it-1) V(it-1)
    const int t = cp; cp = cs; cs = cn; cn = t;
  }
  // ---- drain: softmax + PV of tile 31 ----
  {
    uint2 pk[2][2][4];
    softmax_pack(pk);
    pv(Vs + cp * 4096, pk);
  }

  // ---- epilogue: O^T/l -> ctx[b][t][h*64+dk], packed b64 stores ----
  const int b_ = bh >> 4, h = bh & 15;
#pragma unroll
  for (int qt = 0; qt < 2; qt++) {
    float lt = l_[qt];
    lt += __shfl_xor(lt, 32, 64);            // halves hold complementary s
    const float inv = 1.0f / lt;
    const int t = q0 + w * 64 + qt * 32 + l32;
    unsigned short* cr = ctx + ((size_t)(b_ * 2048 + t)) * 1024 + h * 64;
#pragma unroll
    for (int mt = 0; mt < 2; mt++)
#pragma unroll
      for (int g = 0; g < 4; g++) {
        uint2 pkv;
        pkv.x = pack2bf(o[qt][mt][g * 4 + 0] * inv, o[qt][mt][g * 4 + 1] * inv);
        pkv.y = pack2bf(o[qt][mt][g * 4 + 2] * inv, o[qt][mt][g * 4 + 3] * inv);
        *(uint2*)(cr + mt * 32 + g * 8 + hi * 4) = pkv;
      }
  }
}

// ---------------- Kernel 3: output GEMM ----------------
__global__ __launch_bounds__(256) void out_gemm(const unsigned short* __restrict__ ctx,
                                                const unsigned short* __restrict__ wt,
                                                const float* __restrict__ bias,
                                                float* __restrict__ out) {
  __shared__ __align__(16) unsigned short As[128 * 64];
  __shared__ __align__(16) unsigned short Bs[128 * 64];
  f32x4 acc[4][4];
#pragma unroll
  for (int i = 0; i < 4; i++)
#pragma unroll
    for (int j = 0; j < 4; j++) acc[i][j] = (f32x4){0.f, 0.f, 0.f, 0.f};

  const int m0 = blockIdx.x * 128, n0 = blockIdx.y * 128;
  gemm128(ctx, wt, m0, n0, As, Bs, acc);

  const int tid = threadIdx.x;
  const int w = tid >> 6, lane = tid & 63, quad = lane >> 4, l16 = lane & 15;
  const int wm = (w >> 1) * 64, wn = (w & 1) * 64;
#pragma unroll
  for (int jn = 0; jn < 4; jn++) {
    const int n = n0 + wn + jn * 16 + l16;
    const float bv = bias[n];
#pragma unroll
    for (int i = 0; i < 4; i++) {
#pragma unroll
      for (int r = 0; r < 4; r++) {
        const int m = m0 + wm + i * 16 + quad * 4 + r;
        out[(size_t)m * 1024 + n] = acc[i][jn][r] + bv;
      }
    }
  }
}

extern "C" void kernel_launch(void* const* d_in, const int* in_sizes, int n_in,
                              void* d_out, int out_size, void* d_ws, size_t ws_size,
                              hipStream_t stream) {
  const float* x     = (const float*)d_in[0];
  const float* w_qkv = (const float*)d_in[1];
  const float* b_qkv = (const float*)d_in[2];
  const float* w_out = (const float*)d_in[3];
  const float* b_out = (const float*)d_in[4];
  float* out = (float*)d_out;

  char* ws = (char*)d_ws;
  unsigned short* XB  = (unsigned short*)(ws + 0);
  unsigned short* WQT = (unsigned short*)(ws + 16777216);
  unsigned short* WOT = (unsigned short*)(ws + 23068672);
  unsigned short* Qp  = (unsigned short*)(ws + 25165824);
  unsigned short* Kp  = (unsigned short*)(ws + 41943040);
  unsigned short* VTp = (unsigned short*)(ws + 58720256);
  unsigned short* CTX = (unsigned short*)(ws + 75497472);

  prepass<<<9216, 256, 0, stream>>>(x, XB, w_qkv, WQT, w_out, WOT);
  qkv_gemm<<<384, 512, 0, stream>>>(XB, WQT, b_qkv, Qp, Kp, VTp);
  flash_attn<<<dim3(64, 8), 256, 0, stream>>>(Qp, Kp, VTp, CTX);
  out_gemm<<<dim3(64, 8), 256, 0, stream>>>(CTX, WOT, b_out, out);
}

// Round 9
// 268.386 us; speedup vs baseline: 1.0315x; 1.0315x over previous
//
#include <hip/hip_runtime.h>
#include <hip/hip_bf16.h>

// MultiHeadSelfAttention: B=4, T=2048, D=1024, H=16, dk=64
// Pipeline: fused prepass -> QKV GEMM (256^2 8-phase, m201-style) ->
//           flash attention (R1 structure) -> out GEMM (m97-style)
//
// R9 = R8 with ONE change: the qkv block swizzle.
// R8 diagnosis: qkv 110us, MfmaUtil 18%, VALUBusy 9.8%, FETCH 103.5MB vs
// 22MB unique input (4.7x L2 over-fetch). Old swizzle (mt=swz&31) gave each
// XCD 48 DISTINCT A-panels = 24MB >> 4MB L2 -> every A stage L2-missed
// (~600-900cy) > the 4-phase A-cover -> vmcnt stall every K-tile.
// New swizzle: 8 XCD rectangles of 8mt x 6nt -> per-XCD A 4MB + B 3MB;
// A panels reused 6x, B 8x in L2 -> stages become ~200cy L2 hits.
//
//   * flash_attn: exact R1 (89.6-91 us measured, local optimum).
//   * out_gemm: m97 gemm128 (control, unchanged).
//
// Workspace layout (bytes), total 92,274,688 (88 MiB):
//   XB   @ 0         : x as bf16              [8192][1024]        16 MiB
//   WQT  @ 16777216  : w_qkv^T as bf16        [3072][1024]         6 MiB
//   WOT  @ 23068672  : w_out^T as bf16        [1024][1024]         2 MiB
//   Q    @ 25165824  : bf16 [4][16][2048][64] (pre-scaled)        16 MiB
//   K    @ 41943040  : bf16 [4][16][2048][64]                     16 MiB
//   VT   @ 58720256  : bf16 [4][16][64][2048]  (V transposed)     16 MiB
//   CTX  @ 75497472  : bf16 [8192][1024]                          16 MiB

using v8bf  = __attribute__((ext_vector_type(8))) __bf16;
using f32x4 = __attribute__((ext_vector_type(4))) float;
using f32x16 = __attribute__((ext_vector_type(16))) float;
typedef unsigned int uv2 __attribute__((ext_vector_type(2)));

__device__ __forceinline__ unsigned short f2bf(float f) {
  union { float f; unsigned int u; } v; v.f = f;
  unsigned int u = v.u;
  u += 0x7FFFu + ((u >> 16) & 1u);   // round-to-nearest-even
  return (unsigned short)(u >> 16);
}

#if __has_builtin(__builtin_amdgcn_cvt_pk_bf16_f32)
__device__ __forceinline__ unsigned int pack2bf(float a, float b) {
  typedef __bf16 bf16x2 __attribute__((ext_vector_type(2)));
  bf16x2 r = __builtin_amdgcn_cvt_pk_bf16_f32(a, b);   // dst.lo=a, dst.hi=b
  return __builtin_bit_cast(unsigned int, r);
}
#else
__device__ __forceinline__ unsigned int pack2bf(float a, float b) {
  return (unsigned int)f2bf(a) | ((unsigned int)f2bf(b) << 16);
}
#endif

// async global->LDS, 16B per lane. LDS dest = wave-uniform base + lane*16.
__device__ __forceinline__ void async16(const void* g, void* l) {
  __builtin_amdgcn_global_load_lds(
      (__attribute__((address_space(1))) void*)g,
      (__attribute__((address_space(3))) void*)l, 16, 0, 0);
}

// ---------------- Kernel 0: fused prepass ----------------
// blocks [0,8192):    x fp32 -> bf16 contiguous (4 floats/thread)
// blocks [8192,8960): w_qkv [1024][3072] -> WQT [3072][1024] (64x64 tiles)
// blocks [8960,9216): w_out [1024][1024] -> WOT [1024][1024]
__global__ __launch_bounds__(256) void prepass(const float* __restrict__ x,
                                               unsigned short* __restrict__ XB,
                                               const float* __restrict__ wq,
                                               unsigned short* __restrict__ WQT,
                                               const float* __restrict__ wo,
                                               unsigned short* __restrict__ WOT) {
  const int bid = blockIdx.x;
  if (bid < 8192) {
    const int i = (bid * 256 + threadIdx.x) * 4;
    float4 v = *(const float4*)(x + i);
    ushort4 o;
    o.x = f2bf(v.x); o.y = f2bf(v.y); o.z = f2bf(v.z); o.w = f2bf(v.w);
    *(ushort4*)(XB + i) = o;
  } else {
    const float* in; unsigned short* out; int N, tb;
    if (bid < 8960) { in = wq; out = WQT; N = 3072; tb = bid - 8192; }
    else            { in = wo; out = WOT; N = 1024; tb = bid - 8960; }
    __shared__ unsigned short tile[64][65];
    const int k0 = (tb & 15) * 64, n0 = (tb >> 4) * 64;   // K=1024 -> 16 k-tiles
    for (int i = threadIdx.x; i < 4096; i += 256) {
      int r = i >> 6, c = i & 63;
      tile[r][c] = f2bf(in[(size_t)(k0 + r) * N + n0 + c]);
    }
    __syncthreads();
    for (int i = threadIdx.x; i < 4096; i += 256) {
      int r = i >> 6, c = i & 63;
      out[(size_t)(n0 + r) * 1024 + k0 + c] = tile[c][r];
    }
  }
}

// ---------------- m97-style GEMM mainloop (out_gemm only) ----------------
__device__ __forceinline__ void gemm128(const unsigned short* __restrict__ A,
                                        const unsigned short* __restrict__ Bt,
                                        int m0, int n0,
                                        unsigned short* As, unsigned short* Bs,
                                        f32x4 acc[4][4]) {
  const int tid = threadIdx.x;
  const int w = tid >> 6, lane = tid & 63, quad = lane >> 4, l16 = lane & 15;
  const int wm = (w >> 1) * 64, wn = (w & 1) * 64;

  const int srow = w * 32 + (lane >> 3);
  const int cg = (lane & 7) ^ (lane >> 3);
  const size_t a_g = (size_t)(m0 + srow) * 1024 + cg * 8;
  const size_t b_g = (size_t)(n0 + srow) * 1024 + cg * 8;
  const int lds_off = srow * 64 + (lane & 7) * 8;

  const int l7 = l16 & 7;
  const int a_rd0 = (wm + l16) * 128 + ((quad ^ l7) << 4);
  const int a_rd1 = (wm + l16) * 128 + (((4 + quad) ^ l7) << 4);
  const int b_rd0 = (wn + l16) * 128 + ((quad ^ l7) << 4);
  const int b_rd1 = (wn + l16) * 128 + (((4 + quad) ^ l7) << 4);

  for (int k0 = 0; k0 < 1024; k0 += 64) {
#pragma unroll
    for (int j = 0; j < 4; j++) {
      async16(A + a_g + (size_t)j * 8192 + k0, As + lds_off + j * 512);
      async16(Bt + b_g + (size_t)j * 8192 + k0, Bs + lds_off + j * 512);
    }
    __syncthreads();
#pragma unroll
    for (int ks = 0; ks < 2; ks++) {
      v8bf af[4], bfr[4];
#pragma unroll
      for (int i = 0; i < 4; i++) {
        af[i]  = *(const v8bf*)((const char*)As + (ks ? a_rd1 : a_rd0) + i * 2048);
        bfr[i] = *(const v8bf*)((const char*)Bs + (ks ? b_rd1 : b_rd0) + i * 2048);
      }
#pragma unroll
      for (int i = 0; i < 4; i++)
#pragma unroll
        for (int jn = 0; jn < 4; jn++)
          acc[i][jn] = __builtin_amdgcn_mfma_f32_16x16x32_bf16(af[i], bfr[jn], acc[i][jn], 0, 0, 0);
    }
    __syncthreads();
  }
}

// ---------------- Kernel 1: QKV GEMM, 256^2 8-phase ----------------
// 512 threads / 8 waves (2M x 4N), per-wave 128x64 C = acc[8][4].
// LDS: A 2x[256][64] (64KB) + B 2x[256][64] (64KB) = 128 KiB, 1 block/CU.
// Phase = one C-quadrant (32 rows) x K=64 = 16 MFMA. 4 phases/K-tile,
// 16 K-tiles (K=1024). Per phase: ds-reads (q0: B 8 + A 4; else A 4),
// stage ONE half-tile (128 rows x 64 K, 2 gload_lds/thread) into a
// region freed by the release schedule:
//   q0 -> A(kt+1)h0   (A buf kt+1 parity: released after kt-1 q3)
//   q1 -> A(kt+1)h1
//   q2 -> B(kt+2)h0   (B buf kt parity: released after kt q0)
//   q3 -> B(kt+2)h1
// vmcnt(4) at q0 (halves staged after K-tile kt's last: exactly B(kt+1)
// h0/h1 = 4 loads); vmcnt(0) at kt=15 q0. Never drained elsewhere.
__global__ __launch_bounds__(512, 2) void qkv_gemm(const unsigned short* __restrict__ xb,
                                                   const unsigned short* __restrict__ wt,
                                                   const float* __restrict__ bias,
                                                   unsigned short* __restrict__ Q,
                                                   unsigned short* __restrict__ K,
                                                   unsigned short* __restrict__ VT) {
  __shared__ __align__(16) unsigned char pool[131072];        // 128 KiB
  unsigned short* AsL = (unsigned short*)pool;                // 2 x 32 KB
  unsigned short* BsL = (unsigned short*)(pool + 65536);      // 2 x 32 KB
  unsigned short* Tr  = (unsigned short*)pool;                // reused post-GEMM

  const int tid = threadIdx.x;
  const int wid = tid >> 6, lane = tid & 63;
  const int quad = lane >> 4, l16 = lane & 15, l7 = l16 & 7;
  const int wm = (wid >> 2) * 128, wn = (wid & 3) * 64;

  // L2-locality swizzle (R9): 8 XCD rectangles of 8mt x 6nt.
  // Per-XCD working set A 4MB + B 3MB (was 24MB+6MB with mt=swz&31) ->
  // A panels L2-reused 6x, B 8x; stages become L2 hits inside the
  // 4-phase prefetch cover. Bijective over 384 blocks (id&7 = XCD).
  const int id = blockIdx.x;
  const int xcd = id & 7, s = id >> 3;         // s in [0,48)
  const int mt = (xcd & 3) * 8 + (s & 7);      // [0,32)
  const int nt = (xcd >> 2) * 6 + (s >> 3);    // [0,12)
  const int m0 = mt * 256, n0 = nt * 256;

  const int cg = (lane & 7) ^ (lane >> 3);    // pre-swizzled global chunk

  f32x4 acc[8][4];
#pragma unroll
  for (int i = 0; i < 8; i++)
#pragma unroll
    for (int j = 0; j < 4; j++) acc[i][j] = (f32x4){0.f, 0.f, 0.f, 0.f};

  // stage one 128x64 half-tile (2 x gload_lds / thread, 16B each)
  auto stageHalf = [&](int isB, int h, int kt) {
    const unsigned short* G = isB ? wt : xb;
    const int rbase = (isB ? n0 : m0) + h * 128;
    unsigned short* dst = (isB ? BsL : AsL) + (kt & 1) * 16384 + h * 8192
                          + wid * 512 + lane * 8;   // = uniform + lane*16B
#pragma unroll
    for (int j = 0; j < 2; j++)
      async16(G + (size_t)(rbase + j * 64 + wid * 8 + (lane >> 3)) * 1024
                + kt * 64 + cg * 8,
              dst + j * 4096);
  };

  // prologue: B0h0,B0h1,A0h0,A0h1,B1h0,B1h1 (6 halves, 12 loads/thread)
  stageHalf(1, 0, 0); stageHalf(1, 1, 0);
  stageHalf(0, 0, 0); stageHalf(0, 1, 0);
  stageHalf(1, 0, 1); stageHalf(1, 1, 1);
  asm volatile("s_waitcnt vmcnt(4)" ::: "memory");   // K-tile 0 complete
  __builtin_amdgcn_s_barrier();

  const int rB = wn & 64;                  // row base within B half
  v8bf bfr[4][2];                          // B-frags persist across a K-tile

  for (int kt = 0; kt < 16; ++kt) {
    const unsigned short* Ah = AsL + (kt & 1) * 16384 + (wid >> 2) * 8192;
    const unsigned short* Bh = BsL + (kt & 1) * 16384 + ((wid >> 1) & 1) * 8192;
#pragma unroll
    for (int q = 0; q < 4; ++q) {
      if (q == 0) {
        if (kt == 15)     asm volatile("s_waitcnt vmcnt(0)" ::: "memory");
        else if (kt > 0)  asm volatile("s_waitcnt vmcnt(4)" ::: "memory");
      }
      // ds-reads for this phase
      if (q == 0) {
#pragma unroll
        for (int j = 0; j < 4; j++)
#pragma unroll
          for (int ks = 0; ks < 2; ks++)
            bfr[j][ks] = *(const v8bf*)((const char*)Bh +
                (rB + j * 16 + l16) * 128 + (((ks * 4 + quad) ^ l7) << 4));
      }
      v8bf af[2][2];
#pragma unroll
      for (int i = 0; i < 2; i++)
#pragma unroll
        for (int ks = 0; ks < 2; ks++)
          af[i][ks] = *(const v8bf*)((const char*)Ah +
              (q * 32 + i * 16 + l16) * 128 + (((ks * 4 + quad) ^ l7) << 4));
      // stage one half-tile into a released region
      if (q <= 1) { if (kt < 15) stageHalf(0, q, kt + 1); }
      else        { if (kt < 14) stageHalf(1, q - 2, kt + 2); }
      if (q == 0) asm volatile("s_waitcnt lgkmcnt(8)" ::: "memory");
      __builtin_amdgcn_s_barrier();
      asm volatile("s_waitcnt lgkmcnt(0)" ::: "memory");
      __builtin_amdgcn_s_setprio(1);
#pragma unroll
      for (int i = 0; i < 2; i++)
#pragma unroll
        for (int ks = 0; ks < 2; ks++)
#pragma unroll
          for (int j = 0; j < 4; j++)
            acc[q * 2 + i][j] = __builtin_amdgcn_mfma_f32_16x16x32_bf16(
                af[i][ks], bfr[j][ks], acc[q * 2 + i][j], 0, 0, 0);
      __builtin_amdgcn_s_setprio(0);
      __builtin_amdgcn_s_barrier();
    }
  }

  // ---------------- epilogue ----------------
  const int seg = n0 >> 10;
  if (seg < 2) {
    const float sc = (seg == 0) ? 0.18033688011112042f : 1.0f;  // 0.125*log2(e)
    unsigned short* dst = (seg == 0) ? Q : K;
#pragma unroll
    for (int j = 0; j < 4; j++) {
      const int n = n0 + wn + j * 16 + l16;
      const float bv = bias[n];
      const int nn = n & 1023, h = nn >> 6, d = nn & 63;
#pragma unroll
      for (int i = 0; i < 8; i++) {
#pragma unroll
        for (int r = 0; r < 4; r++) {
          const int m = m0 + wm + i * 16 + quad * 4 + r;
          const int b_ = m >> 11, t = m & 2047;
          dst[(((size_t)(b_ * 16 + h)) * 2048 + t) * 64 + d] =
              f2bf((acc[i][j][r] + bv) * sc);
        }
      }
    }
  } else {
    // V: transpose 256x256 tile via LDS in two 128-col passes
    const int TP = 136;
#pragma unroll
    for (int ph = 0; ph < 2; ph++) {
      if ((wid >> 2) == ph) {
#pragma unroll
        for (int j = 0; j < 4; j++) {
          const int nl = wn + j * 16 + l16;          // 0..255
          const float bv = bias[n0 + nl];
#pragma unroll
          for (int i = 0; i < 8; i++) {
            const int ml = i * 16 + quad * 4;        // local col 0..127
            ushort4 v4;
            v4.x = f2bf(acc[i][j][0] + bv);
            v4.y = f2bf(acc[i][j][1] + bv);
            v4.z = f2bf(acc[i][j][2] + bv);
            v4.w = f2bf(acc[i][j][3] + bv);
            *(ushort4*)&Tr[nl * TP + ml] = v4;
          }
        }
      }
      __syncthreads();
      {
        const int rl = tid >> 1, cb = (tid & 1) * 64;
        const int h0 = (n0 & 1023) >> 6;
        const int h = h0 + (rl >> 6), d = rl & 63;
        const int b_ = m0 >> 11;
        const int t0 = (m0 & 2047) + ph * 128 + cb;
        unsigned short* dstp = VT + (((size_t)(b_ * 16 + h)) * 64 + d) * 2048 + t0;
        const unsigned short* src = &Tr[rl * TP + cb];
#pragma unroll
        for (int c = 0; c < 8; c++)   // 8 x uint4 = 64 shorts
          *(uint4*)(dstp + c * 8) = *(const uint4*)(src + c * 8);
      }
      __syncthreads();
    }
  }
}

// ---------------- Kernel 2: flash attention (S^T, pipelined softmax) ----------------
// EXACT R1 structure (89.6-91 us measured). Grid (x=bh 64, y=qtile 8): XCD = bh%8.
// Step i body: softmax(st of tile i-1) [VALU] + S(tile i) [matrix, K LDS] +
// PV(i-1) [matrix, V LDS]. 64-s K/V tiles, TRIPLE-buffered. One barrier/step.
__global__ __launch_bounds__(256, 2) void flash_attn(const unsigned short* __restrict__ Q,
                                                     const unsigned short* __restrict__ K,
                                                     const unsigned short* __restrict__ VT,
                                                     unsigned short* __restrict__ ctx) {
  const int bh    = blockIdx.x;   // 0..63  (x: keeps same-bh blocks on one XCD)
  const int qtile = blockIdx.y;   // 0..7
  const int tid = threadIdx.x;
  const int w = tid >> 6, lane = tid & 63, hi = lane >> 5, l32 = lane & 31;
  const int q0 = qtile * 256;

  const unsigned short* Qb = Q  + (size_t)bh * 2048 * 64;
  const unsigned short* Kb = K  + (size_t)bh * 2048 * 64;
  const unsigned short* Vb = VT + (size_t)bh * 64 * 2048;

  // triple-buffered K [64 s][64 dk] and V [64 dk][64 s] tiles, XOR-swizzled
  // 16B chunks (slot = chunk ^ (row&7)) for conflict-free b128 reads.
  __shared__ __align__(16) unsigned short Ks[3 * 4096];
  __shared__ __align__(16) unsigned short Vs[3 * 4096];

  const int sr = w * 8 + (lane >> 3);
  const int cg = (lane & 7) ^ ((lane >> 3) & 7);
  const int lds_off = sr * 64 + (lane & 7) * 8;

  // persistent Q B-frags for 2 q-tiles (Q pre-scaled by 0.125*log2e)
  v8bf qf[2][4];
#pragma unroll
  for (int qt = 0; qt < 2; qt++) {
    const int qrow = q0 + w * 64 + qt * 32 + l32;
#pragma unroll
    for (int kc = 0; kc < 4; kc++)
      qf[qt][kc] = *(const v8bf*)(Qb + (size_t)qrow * 64 + kc * 16 + hi * 8);
  }

  f32x16 o[2][2];     // [qt][mt] O^T accumulators
  f32x16 st[2][2];    // [qt][sf] score/prob tile, pipelined across steps
  float l_[2] = {0.f, 0.f};
#pragma unroll
  for (int qt = 0; qt < 2; qt++)
#pragma unroll
    for (int mt = 0; mt < 2; mt++)
#pragma unroll
      for (int r = 0; r < 16; r++) o[qt][mt][r] = 0.f;

  // persistent zero C-operand: computeS seeds its first MFMA from this
  // instead of 64 v_mov zero-fills per step (costs 16 VGPRs, saves ~128cy/step)
  f32x16 fz;
#pragma unroll
  for (int r = 0; r < 16; r++) fz[r] = 0.f;

  auto stage = [&](int buf, int s0) {
    unsigned short* Kd = Ks + buf * 4096;
    unsigned short* Vd = Vs + buf * 4096;
#pragma unroll
    for (int j = 0; j < 2; j++) {
      async16(Kb + (size_t)(s0 + sr + j * 32) * 64 + cg * 8, Kd + lds_off + j * 2048);
      async16(Vb + (size_t)(sr + j * 32) * 2048 + s0 + cg * 8, Vd + lds_off + j * 2048);
    }
  };

  const int l7 = l32 & 7;

  // S^T(tile) = K_tile . Q^T into st (fresh accumulate, C seeded from fz)
  auto computeS = [&](const unsigned short* Kc) {
#pragma unroll
    for (int sf = 0; sf < 2; sf++) {
      v8bf ak[4];
#pragma unroll
      for (int kc = 0; kc < 4; kc++)
        ak[kc] = *(const v8bf*)((const char*)Kc +
                   (sf * 32 + l32) * 128 + (((2 * kc + hi) ^ l7) << 4));
#pragma unroll
      for (int qt = 0; qt < 2; qt++) {
        f32x16 s = __builtin_amdgcn_mfma_f32_32x32x16_bf16(ak[0], qf[qt][0], fz, 0, 0, 0);
#pragma unroll
        for (int kc = 1; kc < 4; kc++)
          s = __builtin_amdgcn_mfma_f32_32x32x16_bf16(ak[kc], qf[qt][kc], s, 0, 0, 0);
        st[qt][sf] = s;
      }
    }
  };

  // exp2(st) in place, accumulate l, pack to bf16 pairs (frees st for next S)
  auto softmax_pack = [&](uint2 pk[2][2][4]) {
#pragma unroll
    for (int qt = 0; qt < 2; qt++) {
      float a = 0.f;
#pragma unroll
      for (int sf = 0; sf < 2; sf++)
#pragma unroll
        for (int r = 0; r < 16; r++) {
          const float pv = __builtin_amdgcn_exp2f(st[qt][sf][r]);
          st[qt][sf][r] = pv;
          a += pv;
        }
      l_[qt] += a;
#pragma unroll
      for (int sf = 0; sf < 2; sf++)
#pragma unroll
        for (int g = 0; g < 4; g++) {
          pk[qt][sf][g].x = pack2bf(st[qt][sf][g * 4 + 0], st[qt][sf][g * 4 + 1]);
          pk[qt][sf][g].y = pack2bf(st[qt][sf][g * 4 + 2], st[qt][sf][g * 4 + 3]);
        }
    }
  };

  // C-layout -> B-frag half-swap transform + PV accumulate.
  // v_permlane32_swap_b32(a,b): a' = {a.lo, b.lo}, b' = {a.hi, b.hi} — one
  // instruction yields BOTH B-frag words; replaces ds_bpermute shfl + selects.
  auto pv = [&](const unsigned short* Vc, uint2 pk[2][2][4]) {
    v8bf vf[2][4];
#pragma unroll
    for (int mt = 0; mt < 2; mt++)
#pragma unroll
      for (int kc = 0; kc < 4; kc++)
        vf[mt][kc] = *(const v8bf*)((const char*)Vc +
                       (mt * 32 + l32) * 128 + (((2 * kc + hi) ^ l7) << 4));
#pragma unroll
    for (int qt = 0; qt < 2; qt++) {
#pragma unroll
      for (int kc = 0; kc < 4; kc++) {
        const int sf = kc >> 1, c2 = (kc & 1) * 2;
        const uint2 olo = pk[qt][sf][c2];
        const uint2 ohi = pk[qt][sf][c2 + 1];
        uint4 u;
#if __has_builtin(__builtin_amdgcn_permlane32_swap)
        uv2 rx = __builtin_amdgcn_permlane32_swap(olo.x, ohi.x, false, false);
        uv2 ry = __builtin_amdgcn_permlane32_swap(olo.y, ohi.y, false, false);
        u.x = rx[0]; u.y = ry[0]; u.z = rx[1]; u.w = ry[1];
#else
        uint2 send, recv;
        send.x = hi ? olo.x : ohi.x;
        send.y = hi ? olo.y : ohi.y;
        recv.x = __shfl_xor(send.x, 32, 64);
        recv.y = __shfl_xor(send.y, 32, 64);
        u.x = hi ? recv.x : olo.x;
        u.y = hi ? recv.y : olo.y;
        u.z = hi ? ohi.x : recv.x;
        u.w = hi ? ohi.y : recv.y;
#endif
        const v8bf pf = __builtin_bit_cast(v8bf, u);
#pragma unroll
        for (int mt = 0; mt < 2; mt++)
          o[qt][mt] = __builtin_amdgcn_mfma_f32_32x32x16_bf16(vf[mt][kc], pf, o[qt][mt], 0, 0, 0);
      }
    }
  };

  // ---- prologue: stage tiles 0,1; S(0) ----
  stage(0, 0);
  __syncthreads();          // tile 0 visible
  stage(1, 64);             // into buf 1; drained by the it=1 barrier
  computeS(Ks);             // st = S(tile 0)

  // ---- pipelined main loop: step it handles softmax+PV of it-1, S of it ----
  // rotating buffer indices (cs = it%3, cp = (it-1)%3, cn = (it+1)%3)
  int cs = 1, cp = 0, cn = 2;
  for (int it = 1; it < 32; ++it) {
    __syncthreads();        // stage(it) done; all waves released buf (it+1)%3
    if (it < 31) stage(cn, (it + 1) * 64);
    uint2 pk[2][2][4];
    softmax_pack(pk);                        // VALU/trans on tile it-1
    computeS(Ks + cs * 4096);                // matrix: S(tile it) -> st
    pv(Vs + cp * 4096, pk);                  // matrix+DS: O += P(it-1) V(it-1)
    const int t = cp; cp = cs; cs = cn; cn = t;
  }
  // ---- drain: softmax + PV of tile 31 ----
  {
    uint2 pk[2][2][4];
    softmax_pack(pk);
    pv(Vs + cp * 4096, pk);
  }

  // ---- epilogue: O^T/l -> ctx[b][t][h*64+dk], packed b64 stores ----
  const int b_ = bh >> 4, h = bh & 15;
#pragma unroll
  for (int qt = 0; qt < 2; qt++) {
    float lt = l_[qt];
    lt += __shfl_xor(lt, 32, 64);            // halves hold complementary s
    const float inv = 1.0f / lt;
    const int t = q0 + w * 64 + qt * 32 + l32;
    unsigned short* cr = ctx + ((size_t)(b_ * 2048 + t)) * 1024 + h * 64;
#pragma unroll
    for (int mt = 0; mt < 2; mt++)
#pragma unroll
      for (int g = 0; g < 4; g++) {
        uint2 pkv;
        pkv.x = pack2bf(o[qt][mt][g * 4 + 0] * inv, o[qt][mt][g * 4 + 1] * inv);
        pkv.y = pack2bf(o[qt][mt][g * 4 + 2] * inv, o[qt][mt][g * 4 + 3] * inv);
        *(uint2*)(cr + mt * 32 + g * 8 + hi * 4) = pkv;
      }
  }
}

// ---------------- Kernel 3: output GEMM ----------------
__global__ __launch_bounds__(256) void out_gemm(const unsigned short* __restrict__ ctx,
                                                const unsigned short* __restrict__ wt,
                                                const float* __restrict__ bias,
                                                float* __restrict__ out) {
  __shared__ __align__(16) unsigned short As[128 * 64];
  __shared__ __align__(16) unsigned short Bs[128 * 64];
  f32x4 acc[4][4];
#pragma unroll
  for (int i = 0; i < 4; i++)
#pragma unroll
    for (int j = 0; j < 4; j++) acc[i][j] = (f32x4){0.f, 0.f, 0.f, 0.f};

  const int m0 = blockIdx.x * 128, n0 = blockIdx.y * 128;
  gemm128(ctx, wt, m0, n0, As, Bs, acc);

  const int tid = threadIdx.x;
  const int w = tid >> 6, lane = tid & 63, quad = lane >> 4, l16 = lane & 15;
  const int wm = (w >> 1) * 64, wn = (w & 1) * 64;
#pragma unroll
  for (int jn = 0; jn < 4; jn++) {
    const int n = n0 + wn + jn * 16 + l16;
    const float bv = bias[n];
#pragma unroll
    for (int i = 0; i < 4; i++) {
#pragma unroll
      for (int r = 0; r < 4; r++) {
        const int m = m0 + wm + i * 16 + quad * 4 + r;
        out[(size_t)m * 1024 + n] = acc[i][jn][r] + bv;
      }
    }
  }
}

extern "C" void kernel_launch(void* const* d_in, const int* in_sizes, int n_in,
                              void* d_out, int out_size, void* d_ws, size_t ws_size,
                              hipStream_t stream) {
  const float* x     = (const float*)d_in[0];
  const float* w_qkv = (const float*)d_in[1];
  const float* b_qkv = (const float*)d_in[2];
  const float* w_out = (const float*)d_in[3];
  const float* b_out = (const float*)d_in[4];
  float* out = (float*)d_out;

  char* ws = (char*)d_ws;
  unsigned short* XB  = (unsigned short*)(ws + 0);
  unsigned short* WQT = (unsigned short*)(ws + 16777216);
  unsigned short* WOT = (unsigned short*)(ws + 23068672);
  unsigned short* Qp  = (unsigned short*)(ws + 25165824);
  unsigned short* Kp  = (unsigned short*)(ws + 41943040);
  unsigned short* VTp = (unsigned short*)(ws + 58720256);
  unsigned short* CTX = (unsigned short*)(ws + 75497472);

  prepass<<<9216, 256, 0, stream>>>(x, XB, w_qkv, WQT, w_out, WOT);
  qkv_gemm<<<384, 512, 0, stream>>>(XB, WQT, b_qkv, Qp, Kp, VTp);
  flash_attn<<<dim3(64, 8), 256, 0, stream>>>(Qp, Kp, VTp, CTX);
  out_gemm<<<dim3(64, 8), 256, 0, stream>>>(CTX, WOT, b_out, out);
}

// Round 10
// 261.935 us; speedup vs baseline: 1.0569x; 1.0246x over previous
//
#include <hip/hip_runtime.h>
#include <hip/hip_bf16.h>

// MultiHeadSelfAttention: B=4, T=2048, D=1024, H=16, dk=64
// Pipeline: fused prepass (convert+transposes) -> QKV GEMM (m97-style) ->
//           flash attention (R1 structure) -> out GEMM (m97-style)
//
// R10 = exact restore of R7 (262.4 us, session best).
// Final ledger:
//   * qkv 8-phase 256^2 (R8/R9): slower than gemm128 even after the L2
//     swizzle fix (R9: ~86us vs ~80) — 384 blocks = 1.5 rounds at
//     1 block/CU leaves a third of the wall in prologue/tail, and no
//     co-resident block absorbs stalls (m114 overlap powers gemm128).
//   * qkv coarse counted-vmcnt (R5/R6): +25us (m196's coarse-split case).
//   * flash: R1 structure is the local optimum — occupancy split (R2)
//     and setprio (R3) both measured negative. VALU-issue floor ~56us.
//   * Wins: permlane32_swap+zero-init (-10us), prepass fusion (-3.2us).
//
// Workspace layout (bytes), total 92,274,688 (88 MiB):
//   XB   @ 0         : x as bf16              [8192][1024]        16 MiB
//   WQT  @ 16777216  : w_qkv^T as bf16        [3072][1024]         6 MiB
//   WOT  @ 23068672  : w_out^T as bf16        [1024][1024]         2 MiB
//   Q    @ 25165824  : bf16 [4][16][2048][64] (pre-scaled)        16 MiB
//   K    @ 41943040  : bf16 [4][16][2048][64]                     16 MiB
//   VT   @ 58720256  : bf16 [4][16][64][2048]  (V transposed)     16 MiB
//   CTX  @ 75497472  : bf16 [8192][1024]                          16 MiB

using v8bf  = __attribute__((ext_vector_type(8))) __bf16;
using f32x4 = __attribute__((ext_vector_type(4))) float;
using f32x16 = __attribute__((ext_vector_type(16))) float;
typedef unsigned int uv2 __attribute__((ext_vector_type(2)));

__device__ __forceinline__ unsigned short f2bf(float f) {
  union { float f; unsigned int u; } v; v.f = f;
  unsigned int u = v.u;
  u += 0x7FFFu + ((u >> 16) & 1u);   // round-to-nearest-even
  return (unsigned short)(u >> 16);
}

#if __has_builtin(__builtin_amdgcn_cvt_pk_bf16_f32)
__device__ __forceinline__ unsigned int pack2bf(float a, float b) {
  typedef __bf16 bf16x2 __attribute__((ext_vector_type(2)));
  bf16x2 r = __builtin_amdgcn_cvt_pk_bf16_f32(a, b);   // dst.lo=a, dst.hi=b
  return __builtin_bit_cast(unsigned int, r);
}
#else
__device__ __forceinline__ unsigned int pack2bf(float a, float b) {
  return (unsigned int)f2bf(a) | ((unsigned int)f2bf(b) << 16);
}
#endif

// async global->LDS, 16B per lane. LDS dest = wave-uniform base + lane*16.
__device__ __forceinline__ void async16(const void* g, void* l) {
  __builtin_amdgcn_global_load_lds(
      (__attribute__((address_space(1))) void*)g,
      (__attribute__((address_space(3))) void*)l, 16, 0, 0);
}

// ---------------- Kernel 0: fused prepass ----------------
// blocks [0,8192):    x fp32 -> bf16 contiguous (4 floats/thread)
// blocks [8192,8960): w_qkv [1024][3072] -> WQT [3072][1024] (64x64 tiles)
// blocks [8960,9216): w_out [1024][1024] -> WOT [1024][1024]
__global__ __launch_bounds__(256) void prepass(const float* __restrict__ x,
                                               unsigned short* __restrict__ XB,
                                               const float* __restrict__ wq,
                                               unsigned short* __restrict__ WQT,
                                               const float* __restrict__ wo,
                                               unsigned short* __restrict__ WOT) {
  const int bid = blockIdx.x;
  if (bid < 8192) {
    const int i = (bid * 256 + threadIdx.x) * 4;
    float4 v = *(const float4*)(x + i);
    ushort4 o;
    o.x = f2bf(v.x); o.y = f2bf(v.y); o.z = f2bf(v.z); o.w = f2bf(v.w);
    *(ushort4*)(XB + i) = o;
  } else {
    const float* in; unsigned short* out; int N, tb;
    if (bid < 8960) { in = wq; out = WQT; N = 3072; tb = bid - 8192; }
    else            { in = wo; out = WOT; N = 1024; tb = bid - 8960; }
    __shared__ unsigned short tile[64][65];
    const int k0 = (tb & 15) * 64, n0 = (tb >> 4) * 64;   // K=1024 -> 16 k-tiles
    for (int i = threadIdx.x; i < 4096; i += 256) {
      int r = i >> 6, c = i & 63;
      tile[r][c] = f2bf(in[(size_t)(k0 + r) * N + n0 + c]);
    }
    __syncthreads();
    for (int i = threadIdx.x; i < 4096; i += 256) {
      int r = i >> 6, c = i & 63;
      out[(size_t)(n0 + r) * 1024 + k0 + c] = tile[c][r];
    }
  }
}

// ---------------- m97-style GEMM mainloop ----------------
__device__ __forceinline__ void gemm128(const unsigned short* __restrict__ A,
                                        const unsigned short* __restrict__ Bt,
                                        int m0, int n0,
                                        unsigned short* As, unsigned short* Bs,
                                        f32x4 acc[4][4]) {
  const int tid = threadIdx.x;
  const int w = tid >> 6, lane = tid & 63, quad = lane >> 4, l16 = lane & 15;
  const int wm = (w >> 1) * 64, wn = (w & 1) * 64;

  const int srow = w * 32 + (lane >> 3);
  const int cg = (lane & 7) ^ (lane >> 3);
  const size_t a_g = (size_t)(m0 + srow) * 1024 + cg * 8;
  const size_t b_g = (size_t)(n0 + srow) * 1024 + cg * 8;
  const int lds_off = srow * 64 + (lane & 7) * 8;

  const int l7 = l16 & 7;
  const int a_rd0 = (wm + l16) * 128 + ((quad ^ l7) << 4);
  const int a_rd1 = (wm + l16) * 128 + (((4 + quad) ^ l7) << 4);
  const int b_rd0 = (wn + l16) * 128 + ((quad ^ l7) << 4);
  const int b_rd1 = (wn + l16) * 128 + (((4 + quad) ^ l7) << 4);

  for (int k0 = 0; k0 < 1024; k0 += 64) {
#pragma unroll
    for (int j = 0; j < 4; j++) {
      async16(A + a_g + (size_t)j * 8192 + k0, As + lds_off + j * 512);
      async16(Bt + b_g + (size_t)j * 8192 + k0, Bs + lds_off + j * 512);
    }
    __syncthreads();
#pragma unroll
    for (int ks = 0; ks < 2; ks++) {
      v8bf af[4], bfr[4];
#pragma unroll
      for (int i = 0; i < 4; i++) {
        af[i]  = *(const v8bf*)((const char*)As + (ks ? a_rd1 : a_rd0) + i * 2048);
        bfr[i] = *(const v8bf*)((const char*)Bs + (ks ? b_rd1 : b_rd0) + i * 2048);
      }
#pragma unroll
      for (int i = 0; i < 4; i++)
#pragma unroll
        for (int jn = 0; jn < 4; jn++)
          acc[i][jn] = __builtin_amdgcn_mfma_f32_16x16x32_bf16(af[i], bfr[jn], acc[i][jn], 0, 0, 0);
    }
    __syncthreads();
  }
}

// ---------------- Kernel 1: QKV GEMM + scatter ----------------
// seg 0 (Q): values pre-scaled by 0.125*log2e so flash skips the mul.
// seg 2 (V): 128x128 tile transposed through LDS (reusing the staging pool)
// so VT stores are contiguous 16B chunks instead of 2B/4KB-stride scatter.
__global__ __launch_bounds__(256) void qkv_gemm(const unsigned short* __restrict__ xb,
                                                const unsigned short* __restrict__ wt,
                                                const float* __restrict__ bias,
                                                unsigned short* __restrict__ Q,
                                                unsigned short* __restrict__ K,
                                                unsigned short* __restrict__ VT) {
  __shared__ __align__(16) unsigned char pool[128 * 136 * 2];  // 34816 B
  unsigned short* As = (unsigned short*)pool;
  unsigned short* Bs = (unsigned short*)(pool + 16384);
  unsigned short* Tr = (unsigned short*)pool;                  // reused post-GEMM

  f32x4 acc[4][4];
#pragma unroll
  for (int i = 0; i < 4; i++)
#pragma unroll
    for (int j = 0; j < 4; j++) acc[i][j] = (f32x4){0.f, 0.f, 0.f, 0.f};

  const int m0 = blockIdx.x * 128, n0 = blockIdx.y * 128;
  gemm128(xb, wt, m0, n0, As, Bs, acc);

  const int tid = threadIdx.x;
  const int w = tid >> 6, lane = tid & 63, quad = lane >> 4, l16 = lane & 15;
  const int wm = (w >> 1) * 64, wn = (w & 1) * 64;
  const int seg = n0 >> 10;

  if (seg < 2) {
    const float sc = (seg == 0) ? 0.18033688011112042f : 1.0f;  // 0.125*log2(e)
    unsigned short* dst = (seg == 0) ? Q : K;
#pragma unroll
    for (int jn = 0; jn < 4; jn++) {
      const int n = n0 + wn + jn * 16 + l16;
      const float bv = bias[n];
      const int nn = n & 1023, h = nn >> 6, d = nn & 63;
#pragma unroll
      for (int i = 0; i < 4; i++) {
#pragma unroll
        for (int r = 0; r < 4; r++) {
          const int m = m0 + wm + i * 16 + quad * 4 + r;
          const int b_ = m >> 11, t = m & 2047;
          dst[(((size_t)(b_ * 16 + h)) * 2048 + t) * 64 + d] =
              f2bf((acc[i][jn][r] + bv) * sc);
        }
      }
    }
  } else {
    const int TP = 136;   // transpose pitch (shorts)
#pragma unroll
    for (int jn = 0; jn < 4; jn++) {
      const int nl = wn + jn * 16 + l16;
      const float bv = bias[n0 + nl];
#pragma unroll
      for (int i = 0; i < 4; i++) {
        const int ml = wm + i * 16 + quad * 4;
        ushort4 v4;
        v4.x = f2bf(acc[i][jn][0] + bv);
        v4.y = f2bf(acc[i][jn][1] + bv);
        v4.z = f2bf(acc[i][jn][2] + bv);
        v4.w = f2bf(acc[i][jn][3] + bv);
        *(ushort4*)&Tr[nl * TP + ml] = v4;
      }
    }
    __syncthreads();
    const int rl = tid >> 1, cb = (tid & 1) * 64;     // row (n_local), col base
    const int h0 = (n0 & 1023) >> 6;
    const int h = h0 + (rl >> 6), d = rl & 63;
    const int b_ = m0 >> 11, t = m0 & 2047;
    unsigned short* dst = VT + (((size_t)(b_ * 16 + h)) * 64 + d) * 2048 + t + cb;
    const unsigned short* src = &Tr[rl * TP + cb];
#pragma unroll
    for (int c = 0; c < 8; c++)   // 8 x uint4 = 64 shorts
      *(uint4*)(dst + c * 8) = *(const uint4*)(src + c * 8);
  }
}

// ---------------- Kernel 2: flash attention (S^T, pipelined softmax) ----------------
// EXACT R1 structure (89.6-91 us measured). Grid (x=bh 64, y=qtile 8): XCD = bh%8.
// Step i body: softmax(st of tile i-1) [VALU] + S(tile i) [matrix, K LDS] +
// PV(i-1) [matrix, V LDS]. 64-s K/V tiles, TRIPLE-buffered. One barrier/step.
__global__ __launch_bounds__(256, 2) void flash_attn(const unsigned short* __restrict__ Q,
                                                     const unsigned short* __restrict__ K,
                                                     const unsigned short* __restrict__ VT,
                                                     unsigned short* __restrict__ ctx) {
  const int bh    = blockIdx.x;   // 0..63  (x: keeps same-bh blocks on one XCD)
  const int qtile = blockIdx.y;   // 0..7
  const int tid = threadIdx.x;
  const int w = tid >> 6, lane = tid & 63, hi = lane >> 5, l32 = lane & 31;
  const int q0 = qtile * 256;

  const unsigned short* Qb = Q  + (size_t)bh * 2048 * 64;
  const unsigned short* Kb = K  + (size_t)bh * 2048 * 64;
  const unsigned short* Vb = VT + (size_t)bh * 64 * 2048;

  // triple-buffered K [64 s][64 dk] and V [64 dk][64 s] tiles, XOR-swizzled
  // 16B chunks (slot = chunk ^ (row&7)) for conflict-free b128 reads.
  __shared__ __align__(16) unsigned short Ks[3 * 4096];
  __shared__ __align__(16) unsigned short Vs[3 * 4096];

  const int sr = w * 8 + (lane >> 3);
  const int cg = (lane & 7) ^ ((lane >> 3) & 7);
  const int lds_off = sr * 64 + (lane & 7) * 8;

  // persistent Q B-frags for 2 q-tiles (Q pre-scaled by 0.125*log2e)
  v8bf qf[2][4];
#pragma unroll
  for (int qt = 0; qt < 2; qt++) {
    const int qrow = q0 + w * 64 + qt * 32 + l32;
#pragma unroll
    for (int kc = 0; kc < 4; kc++)
      qf[qt][kc] = *(const v8bf*)(Qb + (size_t)qrow * 64 + kc * 16 + hi * 8);
  }

  f32x16 o[2][2];     // [qt][mt] O^T accumulators
  f32x16 st[2][2];    // [qt][sf] score/prob tile, pipelined across steps
  float l_[2] = {0.f, 0.f};
#pragma unroll
  for (int qt = 0; qt < 2; qt++)
#pragma unroll
    for (int mt = 0; mt < 2; mt++)
#pragma unroll
      for (int r = 0; r < 16; r++) o[qt][mt][r] = 0.f;

  // persistent zero C-operand: computeS seeds its first MFMA from this
  // instead of 64 v_mov zero-fills per step (costs 16 VGPRs, saves ~128cy/step)
  f32x16 fz;
#pragma unroll
  for (int r = 0; r < 16; r++) fz[r] = 0.f;

  auto stage = [&](int buf, int s0) {
    unsigned short* Kd = Ks + buf * 4096;
    unsigned short* Vd = Vs + buf * 4096;
#pragma unroll
    for (int j = 0; j < 2; j++) {
      async16(Kb + (size_t)(s0 + sr + j * 32) * 64 + cg * 8, Kd + lds_off + j * 2048);
      async16(Vb + (size_t)(sr + j * 32) * 2048 + s0 + cg * 8, Vd + lds_off + j * 2048);
    }
  };

  const int l7 = l32 & 7;

  // S^T(tile) = K_tile . Q^T into st (fresh accumulate, C seeded from fz)
  auto computeS = [&](const unsigned short* Kc) {
#pragma unroll
    for (int sf = 0; sf < 2; sf++) {
      v8bf ak[4];
#pragma unroll
      for (int kc = 0; kc < 4; kc++)
        ak[kc] = *(const v8bf*)((const char*)Kc +
                   (sf * 32 + l32) * 128 + (((2 * kc + hi) ^ l7) << 4));
#pragma unroll
      for (int qt = 0; qt < 2; qt++) {
        f32x16 s = __builtin_amdgcn_mfma_f32_32x32x16_bf16(ak[0], qf[qt][0], fz, 0, 0, 0);
#pragma unroll
        for (int kc = 1; kc < 4; kc++)
          s = __builtin_amdgcn_mfma_f32_32x32x16_bf16(ak[kc], qf[qt][kc], s, 0, 0, 0);
        st[qt][sf] = s;
      }
    }
  };

  // exp2(st) in place, accumulate l, pack to bf16 pairs (frees st for next S)
  auto softmax_pack = [&](uint2 pk[2][2][4]) {
#pragma unroll
    for (int qt = 0; qt < 2; qt++) {
      float a = 0.f;
#pragma unroll
      for (int sf = 0; sf < 2; sf++)
#pragma unroll
        for (int r = 0; r < 16; r++) {
          const float pv = __builtin_amdgcn_exp2f(st[qt][sf][r]);
          st[qt][sf][r] = pv;
          a += pv;
        }
      l_[qt] += a;
#pragma unroll
      for (int sf = 0; sf < 2; sf++)
#pragma unroll
        for (int g = 0; g < 4; g++) {
          pk[qt][sf][g].x = pack2bf(st[qt][sf][g * 4 + 0], st[qt][sf][g * 4 + 1]);
          pk[qt][sf][g].y = pack2bf(st[qt][sf][g * 4 + 2], st[qt][sf][g * 4 + 3]);
        }
    }
  };

  // C-layout -> B-frag half-swap transform + PV accumulate.
  // v_permlane32_swap_b32(a,b): a' = {a.lo, b.lo}, b' = {a.hi, b.hi} — one
  // instruction yields BOTH B-frag words; replaces ds_bpermute shfl + selects.
  auto pv = [&](const unsigned short* Vc, uint2 pk[2][2][4]) {
    v8bf vf[2][4];
#pragma unroll
    for (int mt = 0; mt < 2; mt++)
#pragma unroll
      for (int kc = 0; kc < 4; kc++)
        vf[mt][kc] = *(const v8bf*)((const char*)Vc +
                       (mt * 32 + l32) * 128 + (((2 * kc + hi) ^ l7) << 4));
#pragma unroll
    for (int qt = 0; qt < 2; qt++) {
#pragma unroll
      for (int kc = 0; kc < 4; kc++) {
        const int sf = kc >> 1, c2 = (kc & 1) * 2;
        const uint2 olo = pk[qt][sf][c2];
        const uint2 ohi = pk[qt][sf][c2 + 1];
        uint4 u;
#if __has_builtin(__builtin_amdgcn_permlane32_swap)
        uv2 rx = __builtin_amdgcn_permlane32_swap(olo.x, ohi.x, false, false);
        uv2 ry = __builtin_amdgcn_permlane32_swap(olo.y, ohi.y, false, false);
        u.x = rx[0]; u.y = ry[0]; u.z = rx[1]; u.w = ry[1];
#else
        uint2 send, recv;
        send.x = hi ? olo.x : ohi.x;
        send.y = hi ? olo.y : ohi.y;
        recv.x = __shfl_xor(send.x, 32, 64);
        recv.y = __shfl_xor(send.y, 32, 64);
        u.x = hi ? recv.x : olo.x;
        u.y = hi ? recv.y : olo.y;
        u.z = hi ? ohi.x : recv.x;
        u.w = hi ? ohi.y : recv.y;
#endif
        const v8bf pf = __builtin_bit_cast(v8bf, u);
#pragma unroll
        for (int mt = 0; mt < 2; mt++)
          o[qt][mt] = __builtin_amdgcn_mfma_f32_32x32x16_bf16(vf[mt][kc], pf, o[qt][mt], 0, 0, 0);
      }
    }
  };

  // ---- prologue: stage tiles 0,1; S(0) ----
  stage(0, 0);
  __syncthreads();          // tile 0 visible
  stage(1, 64);             // into buf 1; drained by the it=1 barrier
  computeS(Ks);             // st = S(tile 0)

  // ---- pipelined main loop: step it handles softmax+PV of it-1, S of it ----
  // rotating buffer indices (cs = it%3, cp = (it-1)%3, cn = (it+1)%3)
  int cs = 1, cp = 0, cn = 2;
  for (int it = 1; it < 32; ++it) {
    __syncthreads();        // stage(it) done; all waves released buf (it+1)%3
    if (it < 31) stage(cn, (it + 1) * 64);
    uint2 pk[2][2][4];
    softmax_pack(pk);                        // VALU/trans on tile it-1
    computeS(Ks + cs * 4096);                // matrix: S(tile it) -> st
    pv(Vs + cp * 4096, pk);                  // matrix+DS: O += P(it-1) V(it-1)
    const int t = cp; cp = cs; cs = cn; cn = t;
  }
  // ---- drain: softmax + PV of tile 31 ----
  {
    uint2 pk[2][2][4];
    softmax_pack(pk);
    pv(Vs + cp * 4096, pk);
  }

  // ---- epilogue: O^T/l -> ctx[b][t][h*64+dk], packed b64 stores ----
  const int b_ = bh >> 4, h = bh & 15;
#pragma unroll
  for (int qt = 0; qt < 2; qt++) {
    float lt = l_[qt];
    lt += __shfl_xor(lt, 32, 64);            // halves hold complementary s
    const float inv = 1.0f / lt;
    const int t = q0 + w * 64 + qt * 32 + l32;
    unsigned short* cr = ctx + ((size_t)(b_ * 2048 + t)) * 1024 + h * 64;
#pragma unroll
    for (int mt = 0; mt < 2; mt++)
#pragma unroll
      for (int g = 0; g < 4; g++) {
        uint2 pkv;
        pkv.x = pack2bf(o[qt][mt][g * 4 + 0] * inv, o[qt][mt][g * 4 + 1] * inv);
        pkv.y = pack2bf(o[qt][mt][g * 4 + 2] * inv, o[qt][mt][g * 4 + 3] * inv);
        *(uint2*)(cr + mt * 32 + g * 8 + hi * 4) = pkv;
      }
  }
}

// ---------------- Kernel 3: output GEMM ----------------
__global__ __launch_bounds__(256) void out_gemm(const unsigned short* __restrict__ ctx,
                                                const unsigned short* __restrict__ wt,
                                                const float* __restrict__ bias,
                                                float* __restrict__ out) {
  __shared__ __align__(16) unsigned short As[128 * 64];
  __shared__ __align__(16) unsigned short Bs[128 * 64];
  f32x4 acc[4][4];
#pragma unroll
  for (int i = 0; i < 4; i++)
#pragma unroll
    for (int j = 0; j < 4; j++) acc[i][j] = (f32x4){0.f, 0.f, 0.f, 0.f};

  const int m0 = blockIdx.x * 128, n0 = blockIdx.y * 128;
  gemm128(ctx, wt, m0, n0, As, Bs, acc);

  const int tid = threadIdx.x;
  const int w = tid >> 6, lane = tid & 63, quad = lane >> 4, l16 = lane & 15;
  const int wm = (w >> 1) * 64, wn = (w & 1) * 64;
#pragma unroll
  for (int jn = 0; jn < 4; jn++) {
    const int n = n0 + wn + jn * 16 + l16;
    const float bv = bias[n];
#pragma unroll
    for (int i = 0; i < 4; i++) {
#pragma unroll
      for (int r = 0; r < 4; r++) {
        const int m = m0 + wm + i * 16 + quad * 4 + r;
        out[(size_t)m * 1024 + n] = acc[i][jn][r] + bv;
      }
    }
  }
}

extern "C" void kernel_launch(void* const* d_in, const int* in_sizes, int n_in,
                              void* d_out, int out_size, void* d_ws, size_t ws_size,
                              hipStream_t stream) {
  const float* x     = (const float*)d_in[0];
  const float* w_qkv = (const float*)d_in[1];
  const float* b_qkv = (const float*)d_in[2];
  const float* w_out = (const float*)d_in[3];
  const float* b_out = (const float*)d_in[4];
  float* out = (float*)d_out;

  char* ws = (char*)d_ws;
  unsigned short* XB  = (unsigned short*)(ws + 0);
  unsigned short* WQT = (unsigned short*)(ws + 16777216);
  unsigned short* WOT = (unsigned short*)(ws + 23068672);
  unsigned short* Qp  = (unsigned short*)(ws + 25165824);
  unsigned short* Kp  = (unsigned short*)(ws + 41943040);
  unsigned short* VTp = (unsigned short*)(ws + 58720256);
  unsigned short* CTX = (unsigned short*)(ws + 75497472);

  prepass<<<9216, 256, 0, stream>>>(x, XB, w_qkv, WQT, w_out, WOT);
  qkv_gemm<<<dim3(64, 24), 256, 0, stream>>>(XB, WQT, b_qkv, Qp, Kp, VTp);
  flash_attn<<<dim3(64, 8), 256, 0, stream>>>(Qp, Kp, VTp, CTX);
  out_gemm<<<dim3(64, 8), 256, 0, stream>>>(CTX, WOT, b_out, out);
}